// Round 2
// baseline (622.293 us; speedup 1.0000x reference)
//
#include <hip/hip_runtime.h>

// ---------------- problem constants ----------------
#define N_NODES   20000
#define N_EDGES   640000
#define CF        313      // FEAT + NUM_SEM
#define HID       128
#define KC        320      // child K padded to mult of 32 (313 -> 320), 10 ksteps
#define KE        288      // edge K padded (268 -> 288), 9 ksteps
#define ROWB      640      // LDS A-tile row stride in bytes (multiple of 128 for swizzle)
#define TPB_TILES 5        // edge tiles per block (2000 blocks x 5 x 64 edges)

typedef __attribute__((ext_vector_type(8))) short short8;
typedef __attribute__((ext_vector_type(4))) float f32x4;

// barrier WITHOUT vmcnt(0) drain: keeps prefetch loads + atomics in flight.
#define BAR() do { asm volatile("s_waitcnt lgkmcnt(0)" ::: "memory"); \
                   __builtin_amdgcn_s_barrier(); } while (0)

static __device__ __forceinline__ unsigned short f2bf(float f) {
    unsigned u = __float_as_uint(f);
    u = u + 0x7FFFu + ((u >> 16) & 1u);   // RNE
    return (unsigned short)(u >> 16);
}

// ---------------- weight pre-convert: W (KxN f32) -> W^T (N x Kpad bf16) ----
__global__ void prep_weights(const float* __restrict__ Wc,
                             const float* __restrict__ We0,
                             const float* __restrict__ We1,
                             unsigned short* __restrict__ WcT,
                             unsigned short* __restrict__ We0T,
                             unsigned short* __restrict__ We1T) {
    int g = blockIdx.x * 256 + threadIdx.x;           // 448*256 = 114688 exactly
    if (g < 128 * KC) {
        int n = g / KC, k = g % KC;
        WcT[g] = f2bf(k < CF ? Wc[k * 128 + n] : 0.f);
    } else if (g < 128 * KC + 128 * KE) {
        int h = g - 128 * KC;
        int n = h / KE, k = h % KE;
        We0T[h] = f2bf(k < 268 ? We0[k * 128 + n] : 0.f);
    } else {
        int h = g - 128 * KC - 128 * KE;
        int n = h / KE, k = h % KE;
        We1T[h] = f2bf(k < 268 ? We1[k * 128 + n] : 0.f);
    }
}

// ---------------- counting sort by src ----------------
__global__ void hist_kernel(const int* __restrict__ eidx, unsigned* __restrict__ hist) {
    int e = blockIdx.x * 256 + threadIdx.x;           // 2500 blocks
    if (e < N_EDGES) atomicAdd(hist + eidx[2 * e], 1u);
}

__global__ void scan_kernel(const unsigned* __restrict__ hist, unsigned* __restrict__ cursor) {
    __shared__ unsigned part[1024];
    int t = threadIdx.x;                              // 1024 threads, 1 block
    unsigned loc[20];
    unsigned s = 0;
    int base = t * 20;
    if (t < 1000) {
        #pragma unroll
        for (int i = 0; i < 20; ++i) { loc[i] = hist[base + i]; s += loc[i]; }
    }
    part[t] = s;
    __syncthreads();
    for (int off = 1; off < 1024; off <<= 1) {
        unsigned u = (t >= off) ? part[t - off] : 0u;
        __syncthreads();
        part[t] += u;
        __syncthreads();
    }
    if (t < 1000) {
        unsigned run = part[t] - s;                   // exclusive prefix of chunk
        #pragma unroll
        for (int i = 0; i < 20; ++i) { cursor[base + i] = run; run += loc[i]; }
    }
}

__global__ void scatter_kernel(const int* __restrict__ eidx, unsigned* __restrict__ cursor,
                               int2* __restrict__ ssd, int* __restrict__ seid) {
    int e = blockIdx.x * 256 + threadIdx.x;
    if (e < N_EDGES) {
        int s = eidx[2 * e], d = eidx[2 * e + 1];
        unsigned pos = atomicAdd(cursor + s, 1u);
        ssd[pos] = make_int2(s, d);
        seid[pos] = e;
    }
}

// ---------------- child encoder: h = relu(cf @ Wc + bc) * exists ------------
__global__ __launch_bounds__(256, 2)
void child_gemm(const float* __restrict__ cf,          // [20000][313]
                const float* __restrict__ exists,      // [20000]
                const unsigned short* __restrict__ WT, // [128][320] bf16
                const float* __restrict__ bias,        // [128]
                unsigned short* __restrict__ hbf,      // [20000][128] bf16 out
                unsigned int* __restrict__ pmax)       // [128] f32-bits, zeroed
{
    __shared__ __align__(16) unsigned char Alds[64 * ROWB];

    const int tid  = threadIdx.x;
    const int lane = tid & 63;
    const int wave = tid >> 6;
    const int n0   = wave * 32;
    const int tile = blockIdx.x;
    const int row0 = tile * 64;

    short8 bfrag[10][2];
    {
        int col  = n0 + (lane & 15);
        int krow = (lane >> 4) * 8;
        #pragma unroll
        for (int ks = 0; ks < 10; ++ks)
            #pragma unroll
            for (int nt = 0; nt < 2; ++nt)
                bfrag[ks][nt] = *(const short8*)(WT + (col + nt * 16) * KC + ks * 32 + krow);
    }
    float bv[2];
    bv[0] = bias[n0 + (lane & 15)];
    bv[1] = bias[n0 + 16 + (lane & 15)];

    {
        int r = tid >> 2, p = tid & 3;
        int node = row0 + r;
        bool valid = node < N_NODES;
        const float* g = cf + (size_t)node * CF;
        unsigned rbase = r * ROWB;
        unsigned sw = (r & 7) << 4;
        #pragma unroll
        for (int i = 0; i < 10; ++i) {
            int c = p + i * 4;                 // chunk 0..39, 8 bf16 each
            short8 v = {};
            if (valid) {
                #pragma unroll
                for (int kk = 0; kk < 8; ++kk) {
                    int k = c * 8 + kk;
                    if (k < CF) v[kk] = (short)f2bf(g[k]);
                }
            }
            *(short8*)(Alds + ((rbase + c * 16) ^ sw)) = v;
        }
    }
    __syncthreads();

    f32x4 acc[4][2] = {};
    {
        int arow = lane & 15;
        unsigned kb = (lane >> 4) * 16;
        #pragma unroll
        for (int ks = 0; ks < 10; ++ks)
            #pragma unroll
            for (int mt = 0; mt < 4; ++mt) {
                int row = mt * 16 + arow;
                short8 a = *(const short8*)(Alds + (((unsigned)row * ROWB + ks * 64 + kb) ^ ((row & 7) << 4)));
                acc[mt][0] = __builtin_amdgcn_mfma_f32_16x16x32_bf16(a, bfrag[ks][0], acc[mt][0], 0, 0, 0);
                acc[mt][1] = __builtin_amdgcn_mfma_f32_16x16x32_bf16(a, bfrag[ks][1], acc[mt][1], 0, 0, 0);
            }
    }

    {
        int rb = (lane >> 4) * 4;
        #pragma unroll
        for (int nt = 0; nt < 2; ++nt) {
            int col = n0 + nt * 16 + (lane & 15);
            float m = 0.f;
            #pragma unroll
            for (int mt = 0; mt < 4; ++mt)
                #pragma unroll
                for (int j = 0; j < 4; ++j) {
                    int node = row0 + mt * 16 + rb + j;
                    float v = 0.f;
                    if (node < N_NODES) {
                        v = fmaxf(acc[mt][nt][j] + bv[nt], 0.f) * exists[node];
                        hbf[node * 128 + col] = f2bf(v);
                    }
                    m = fmaxf(m, v);
                }
            m = fmaxf(m, __shfl_xor(m, 16));
            m = fmaxf(m, __shfl_xor(m, 32));
            if ((lane >> 4) == 0)
                atomicMax(pmax + col, __float_as_uint(m));
        }
    }
}

// ---------------- edge layer (sorted by src, pipelined, dedup'd atomics) ----
__global__ __launch_bounds__(256, 2)
void edge_layer(const unsigned short* __restrict__ hbf,   // [20000][128] bf16
                const int2* __restrict__ ssd,             // [640000] sorted (src,dst)
                const int* __restrict__ seid,             // [640000] original edge id
                const float* __restrict__ onehot,         // [640000][4]
                const float* __restrict__ efeat,          // [640000][8]
                const unsigned short* __restrict__ WT,    // [128][288] bf16
                const float* __restrict__ bias,           // [128]
                unsigned int* __restrict__ hnext)         // [20000][128] zeroed
{
    __shared__ __align__(16) unsigned char Alds[64 * ROWB];
    __shared__ int srcids[64];

    const int tid  = threadIdx.x;
    const int lane = tid & 63;
    const int wave = tid >> 6;
    const int n0   = wave * 32;

    short8 bfrag[9][2];
    {
        int col  = n0 + (lane & 15);
        int krow = (lane >> 4) * 8;
        #pragma unroll
        for (int ks = 0; ks < 9; ++ks)
            #pragma unroll
            for (int nt = 0; nt < 2; ++nt)
                bfrag[ks][nt] = *(const short8*)(WT + (col + nt * 16) * KE + ks * 32 + krow);
    }
    float bv[2];
    bv[0] = bias[n0 + (lane & 15)];
    bv[1] = bias[n0 + 16 + (lane & 15)];

    const int r = tid >> 2, p = tid & 3;
    const unsigned rbase = r * ROWB;
    const unsigned sw = (r & 7) << 4;

    // zero constant pad chunks 34,35 once (K = 280..319 region beyond ef)
    if (p >= 2) {
        short8 z = {};
        *(short8*)(Alds + ((rbase + (32 + p) * 16) ^ sw)) = z;
    }

    const int t0 = blockIdx.x * TPB_TILES;
    const int tend = t0 + TPB_TILES;

    // ---- prologue: indices + issue loads for tile t0; indices for t0+1 ----
    int2 sd   = ssd[t0 * 64 + r];
    int  eid  = seid[t0 * 64 + r];
    short8 hreg[8];
    {
        const short8* hs = (const short8*)(hbf + (size_t)sd.x * 128);
        const short8* hd = (const short8*)(hbf + (size_t)sd.y * 128);
        #pragma unroll
        for (int i = 0; i < 8; ++i) { int c = p + i * 4; hreg[i] = (c < 16) ? hs[c] : hd[c - 16]; }
    }
    float4 oh4, efl, efh;
    if (p == 0)      { oh4 = *(const float4*)(onehot + 4 * (size_t)eid); efl = *(const float4*)(efeat + 8 * (size_t)eid); }
    else if (p == 1) { efh = *(const float4*)(efeat + 8 * (size_t)eid + 4); }
    int2 sd_n  = ssd[(t0 + 1) * 64 + r];
    int  eid_n = seid[(t0 + 1) * 64 + r];

    for (int t = t0; t < tend; ++t) {
        BAR();                               // prev MFMA's LDS reads done
        // ---- write LDS tile t (waits vmcnt for hreg/ef only) ----
        #pragma unroll
        for (int i = 0; i < 8; ++i) {
            int c = p + i * 4;
            *(short8*)(Alds + ((rbase + c * 16) ^ sw)) = hreg[i];
        }
        if (p == 0) {
            srcids[r] = sd.x;
            short8 v;
            v[0] = (short)f2bf(oh4.x); v[1] = (short)f2bf(oh4.y);
            v[2] = (short)f2bf(oh4.z); v[3] = (short)f2bf(oh4.w);
            v[4] = (short)f2bf(efl.x); v[5] = (short)f2bf(efl.y);
            v[6] = (short)f2bf(efl.z); v[7] = (short)f2bf(efl.w);
            *(short8*)(Alds + ((rbase + 32 * 16) ^ sw)) = v;
        } else if (p == 1) {
            short8 v = {};
            v[0] = (short)f2bf(efh.x); v[1] = (short)f2bf(efh.y);
            v[2] = (short)f2bf(efh.z); v[3] = (short)f2bf(efh.w);
            *(short8*)(Alds + ((rbase + 33 * 16) ^ sw)) = v;
        }
        // ---- issue prefetch for tile t+1 (in flight across MFMA+epilogue) ----
        if (t + 1 < tend) {
            const short8* hs = (const short8*)(hbf + (size_t)sd_n.x * 128);
            const short8* hd = (const short8*)(hbf + (size_t)sd_n.y * 128);
            #pragma unroll
            for (int i = 0; i < 8; ++i) { int c = p + i * 4; hreg[i] = (c < 16) ? hs[c] : hd[c - 16]; }
            if (p == 0)      { oh4 = *(const float4*)(onehot + 4 * (size_t)eid_n); efl = *(const float4*)(efeat + 8 * (size_t)eid_n); }
            else if (p == 1) { efh = *(const float4*)(efeat + 8 * (size_t)eid_n + 4); }
            sd = sd_n;
            if (t + 2 < tend) { sd_n = ssd[(t + 2) * 64 + r]; eid_n = seid[(t + 2) * 64 + r]; }
        }
        BAR();                               // tile t visible to all waves

        // ---- MFMA ----
        f32x4 acc[4][2] = {};
        {
            int arow = lane & 15;
            unsigned kb = (lane >> 4) * 16;
            #pragma unroll
            for (int ks = 0; ks < 9; ++ks)
                #pragma unroll
                for (int mt = 0; mt < 4; ++mt) {
                    int row = mt * 16 + arow;
                    short8 a = *(const short8*)(Alds + (((unsigned)row * ROWB + ks * 64 + kb) ^ ((row & 7) << 4)));
                    acc[mt][0] = __builtin_amdgcn_mfma_f32_16x16x32_bf16(a, bfrag[ks][0], acc[mt][0], 0, 0, 0);
                    acc[mt][1] = __builtin_amdgcn_mfma_f32_16x16x32_bf16(a, bfrag[ks][1], acc[mt][1], 0, 0, 0);
                }
        }

        // ---- epilogue: bias+relu, run-dedup'd atomicMax into h_next[src] ----
        {
            int rb = (lane >> 4) * 4;
            int colbase = n0 + (lane & 15);
            #pragma unroll
            for (int mt = 0; mt < 4; ++mt) {
                int rr = mt * 16 + rb;
                int s0 = srcids[rr], s1 = srcids[rr + 1], s2 = srcids[rr + 2], s3 = srcids[rr + 3];
                #pragma unroll
                for (int nt = 0; nt < 2; ++nt) {
                    unsigned* base = hnext + colbase + nt * 16;
                    float v0 = fmaxf(acc[mt][nt][0] + bv[nt], 0.f);
                    float v1 = fmaxf(acc[mt][nt][1] + bv[nt], 0.f);
                    float v2 = fmaxf(acc[mt][nt][2] + bv[nt], 0.f);
                    float v3 = fmaxf(acc[mt][nt][3] + bv[nt], 0.f);
                    float cur = v0;
                    if (s1 != s0) { atomicMax(base + (size_t)s0 * 128, __float_as_uint(cur)); cur = v1; }
                    else cur = fmaxf(cur, v1);
                    if (s2 != s1) { atomicMax(base + (size_t)s1 * 128, __float_as_uint(cur)); cur = v2; }
                    else cur = fmaxf(cur, v2);
                    if (s3 != s2) { atomicMax(base + (size_t)s2 * 128, __float_as_uint(cur)); cur = v3; }
                    else cur = fmaxf(cur, v3);
                    atomicMax(base + (size_t)s3 * 128, __float_as_uint(cur));
                }
            }
        }
    }
}

// ---------------- h_next (f32) -> h (bf16) + column max + re-zero ----------
__global__ void convert_colmax(unsigned int* __restrict__ hnext,
                               unsigned short* __restrict__ hbf,
                               unsigned int* __restrict__ pslice) {
    int g = blockIdx.x * 256 + threadIdx.x;   // 512*256 = 131072
    int c = g & 127;
    unsigned m = 0;
    for (int r = g >> 7; r < N_NODES; r += 1024) {
        unsigned u = hnext[r * 128 + c];
        hnext[r * 128 + c] = 0;               // pre-zero for next edge layer
        hbf[r * 128 + c] = f2bf(__uint_as_float(u));
        m = max(m, u);                        // valid: non-negative floats
    }
    atomicMax(pslice + c, m);
}

// ---------------- final: out = relu(parent @ Wp + bp) ----------------------
__global__ void final_gemm(const float* __restrict__ parent,  // [384]
                           const float* __restrict__ Wp,      // [384][256]
                           const float* __restrict__ bp,      // [256]
                           float* __restrict__ out) {          // [256]
    __shared__ float p[384];
    int t = threadIdx.x;
    for (int i = t; i < 384; i += 256) p[i] = parent[i];
    __syncthreads();
    float s = bp[t];
    for (int k = 0; k < 384; ++k) s += p[k] * Wp[k * 256 + t];
    out[t] = fmaxf(s, 0.f);
}

// ---------------- launch ----------------------------------------------------
extern "C" void kernel_launch(void* const* d_in, const int* in_sizes, int n_in,
                              void* d_out, int out_size, void* d_ws, size_t ws_size,
                              hipStream_t stream) {
    const float* child_feats  = (const float*)d_in[0];
    const float* child_exists = (const float*)d_in[1];
    const float* onehot       = (const float*)d_in[2];
    const float* efeat        = (const float*)d_in[3];
    const int*   eidx         = (const int*)d_in[4];
    const float* Wc  = (const float*)d_in[5];
    const float* bc  = (const float*)d_in[6];
    const float* We0 = (const float*)d_in[7];
    const float* be0 = (const float*)d_in[8];
    const float* We1 = (const float*)d_in[9];
    const float* be1 = (const float*)d_in[10];
    const float* Wp  = (const float*)d_in[11];
    const float* bp  = (const float*)d_in[12];

    char* ws = (char*)d_ws;
    unsigned short* hbf    = (unsigned short*)(ws);               //  5,120,000
    unsigned int*   hnext  = (unsigned int*)(ws + 5120000);       // 10,240,000
    unsigned short* WcT    = (unsigned short*)(ws + 15360000);    //     81,920
    unsigned short* We0T   = (unsigned short*)(ws + 15441920);    //     73,728
    unsigned short* We1T   = (unsigned short*)(ws + 15515648);    //     73,728
    unsigned int*   parent = (unsigned int*)(ws + 15589376);      //      1,536
    unsigned int*   hist   = (unsigned int*)(ws + 15590912);      //     80,000
    unsigned int*   cursor = (unsigned int*)(ws + 15670912);      //     80,000
    int2*           ssd    = (int2*)(ws + 15750912);              //  5,120,000
    int*            seid   = (int*)(ws + 20870912);               //  2,560,000

    hipMemsetAsync(parent, 0, 384 * 4, stream);
    hipMemsetAsync(hist, 0, N_NODES * 4, stream);
    hipMemsetAsync(hnext, 0, N_NODES * 128 * 4, stream);

    prep_weights<<<448, 256, 0, stream>>>(Wc, We0, We1, WcT, We0T, We1T);
    hist_kernel<<<2500, 256, 0, stream>>>(eidx, hist);
    scan_kernel<<<1, 1024, 0, stream>>>(hist, cursor);
    scatter_kernel<<<2500, 256, 0, stream>>>(eidx, cursor, ssd, seid);

    child_gemm<<<313, 256, 0, stream>>>(child_feats, child_exists, WcT, bc, hbf, parent);

    edge_layer<<<2000, 256, 0, stream>>>(hbf, ssd, seid, onehot, efeat, We0T, be0, hnext);
    convert_colmax<<<512, 256, 0, stream>>>(hnext, hbf, parent + 128);

    edge_layer<<<2000, 256, 0, stream>>>(hbf, ssd, seid, onehot, efeat, We1T, be1, hnext);
    convert_colmax<<<512, 256, 0, stream>>>(hnext, hbf, parent + 256);

    final_gemm<<<1, 256, 0, stream>>>((const float*)parent, Wp, bp, (float*)d_out);
}

// Round 3
// 436.128 us; speedup vs baseline: 1.4269x; 1.4269x over previous
//
#include <hip/hip_runtime.h>

// ---------------- problem constants ----------------
#define N_NODES   20000
#define N_EDGES   640000
#define CF        313      // FEAT + NUM_SEM
#define KC        320      // child K padded (313 -> 320), 10 ksteps
#define ROWB      640      // child LDS A-tile row stride bytes
#define L_CHUNK   50       // edges per 16-lane group: 12800 groups x 50 = 640000

typedef __attribute__((ext_vector_type(8))) short short8;
typedef __attribute__((ext_vector_type(4))) float f32x4;

static __device__ __forceinline__ unsigned short f2bf(float f) {
    unsigned u = __float_as_uint(f);
    u = u + 0x7FFFu + ((u >> 16) & 1u);   // RNE
    return (unsigned short)(u >> 16);
}
static __device__ __forceinline__ float bf2f(unsigned short b) {
    return __uint_as_float(((unsigned)b) << 16);
}
// monotone float->uint encoding (works for any sign)
static __device__ __forceinline__ unsigned encf(float f) {
    unsigned u = __float_as_uint(f);
    return ((int)u >= 0) ? (u ^ 0x80000000u) : ~u;
}
static __device__ __forceinline__ float decf(unsigned u) {
    return (u & 0x80000000u) ? __uint_as_float(u ^ 0x80000000u) : __uint_as_float(~u);
}
static __device__ __forceinline__ int pkbf(float a, float b) {
    return (int)((unsigned)f2bf(a) | ((unsigned)f2bf(b) << 16));
}

// ---------------- weight prep ----------------
// WcT [128][320] bf16 (child W^T);  WabT [256][128] bf16 per layer:
// row n<128: A-col n uses W[k][n]; row n>=128: B-col uses W[128+k][n-128].
__global__ void prep_weights(const float* __restrict__ Wc,
                             const float* __restrict__ We0,
                             const float* __restrict__ We1,
                             unsigned short* __restrict__ WcT,
                             unsigned short* __restrict__ Wab0,
                             unsigned short* __restrict__ Wab1) {
    int g = blockIdx.x * 256 + threadIdx.x;           // 416*256 = 106496 exactly
    if (g < 128 * KC) {
        int n = g / KC, k = g % KC;
        WcT[g] = f2bf(k < CF ? Wc[k * 128 + n] : 0.f);
    } else if (g < 128 * KC + 32768) {
        int h = g - 128 * KC;
        int n = h >> 7, k = h & 127;
        Wab0[h] = f2bf(n < 128 ? We0[k * 128 + n] : We0[(128 + k) * 128 + (n - 128)]);
    } else {
        int h = g - 128 * KC - 32768;
        int n = h >> 7, k = h & 127;
        Wab1[h] = f2bf(n < 128 ? We1[k * 128 + n] : We1[(128 + k) * 128 + (n - 128)]);
    }
}

// ---------------- counting sort by src + ef pre-gather ----------------
__global__ void hist_kernel(const int* __restrict__ eidx, unsigned* __restrict__ hist) {
    int e = blockIdx.x * 256 + threadIdx.x;
    if (e < N_EDGES) atomicAdd(hist + eidx[2 * e], 1u);
}

__global__ void scan_kernel(const unsigned* __restrict__ hist, unsigned* __restrict__ cursor) {
    __shared__ unsigned part[1024];
    int t = threadIdx.x;
    unsigned loc[20];
    unsigned s = 0;
    int base = t * 20;
    if (t < 1000) {
        #pragma unroll
        for (int i = 0; i < 20; ++i) { loc[i] = hist[base + i]; s += loc[i]; }
    }
    part[t] = s;
    __syncthreads();
    for (int off = 1; off < 1024; off <<= 1) {
        unsigned u = (t >= off) ? part[t - off] : 0u;
        __syncthreads();
        part[t] += u;
        __syncthreads();
    }
    if (t < 1000) {
        unsigned run = part[t] - s;
        #pragma unroll
        for (int i = 0; i < 20; ++i) { cursor[base + i] = run; run += loc[i]; }
    }
}

// 32B record per sorted edge: {src, dst, ef[12] as packed bf16}
__global__ void scatter_kernel(const int* __restrict__ eidx,
                               const float* __restrict__ onehot,
                               const float* __restrict__ efeat,
                               unsigned* __restrict__ cursor,
                               int4* __restrict__ es) {
    int e = blockIdx.x * 256 + threadIdx.x;
    if (e >= N_EDGES) return;
    int s = eidx[2 * e], d = eidx[2 * e + 1];
    unsigned pos = atomicAdd(cursor + s, 1u);
    float4 oh = *(const float4*)(onehot + 4 * (size_t)e);
    float4 ea = *(const float4*)(efeat + 8 * (size_t)e);
    float4 eb = *(const float4*)(efeat + 8 * (size_t)e + 4);
    int4 w0, w1;
    w0.x = s; w0.y = d;
    w0.z = pkbf(oh.x, oh.y); w0.w = pkbf(oh.z, oh.w);
    w1.x = pkbf(ea.x, ea.y); w1.y = pkbf(ea.z, ea.w);
    w1.z = pkbf(eb.x, eb.y); w1.w = pkbf(eb.z, eb.w);
    es[2 * (size_t)pos]     = w0;
    es[2 * (size_t)pos + 1] = w1;
}

// ---------------- child encoder: h = relu(cf @ Wc + bc) * exists ------------
__global__ __launch_bounds__(256, 2)
void child_gemm(const float* __restrict__ cf,
                const float* __restrict__ exists,
                const unsigned short* __restrict__ WT,
                const float* __restrict__ bias,
                unsigned short* __restrict__ hbf,
                unsigned int* __restrict__ pmax) {
    __shared__ __align__(16) unsigned char Alds[64 * ROWB];

    const int tid  = threadIdx.x;
    const int lane = tid & 63;
    const int wave = tid >> 6;
    const int n0   = wave * 32;
    const int row0 = blockIdx.x * 64;

    short8 bfrag[10][2];
    {
        int col  = n0 + (lane & 15);
        int krow = (lane >> 4) * 8;
        #pragma unroll
        for (int ks = 0; ks < 10; ++ks)
            #pragma unroll
            for (int nt = 0; nt < 2; ++nt)
                bfrag[ks][nt] = *(const short8*)(WT + (col + nt * 16) * KC + ks * 32 + krow);
    }
    float bv[2];
    bv[0] = bias[n0 + (lane & 15)];
    bv[1] = bias[n0 + 16 + (lane & 15)];

    {
        int r = tid >> 2, p = tid & 3;
        int node = row0 + r;
        bool valid = node < N_NODES;
        const float* g = cf + (size_t)node * CF;
        unsigned rbase = r * ROWB;
        unsigned sw = (r & 7) << 4;
        #pragma unroll
        for (int i = 0; i < 10; ++i) {
            int c = p + i * 4;
            short8 v = {};
            if (valid) {
                #pragma unroll
                for (int kk = 0; kk < 8; ++kk) {
                    int k = c * 8 + kk;
                    if (k < CF) v[kk] = (short)f2bf(g[k]);
                }
            }
            *(short8*)(Alds + ((rbase + c * 16) ^ sw)) = v;
        }
    }
    __syncthreads();

    f32x4 acc[4][2] = {};
    {
        int arow = lane & 15;
        unsigned kb = (lane >> 4) * 16;
        #pragma unroll
        for (int ks = 0; ks < 10; ++ks)
            #pragma unroll
            for (int mt = 0; mt < 4; ++mt) {
                int row = mt * 16 + arow;
                short8 a = *(const short8*)(Alds + (((unsigned)row * ROWB + ks * 64 + kb) ^ ((row & 7) << 4)));
                acc[mt][0] = __builtin_amdgcn_mfma_f32_16x16x32_bf16(a, bfrag[ks][0], acc[mt][0], 0, 0, 0);
                acc[mt][1] = __builtin_amdgcn_mfma_f32_16x16x32_bf16(a, bfrag[ks][1], acc[mt][1], 0, 0, 0);
            }
    }

    {
        int rb = (lane >> 4) * 4;
        #pragma unroll
        for (int nt = 0; nt < 2; ++nt) {
            int col = n0 + nt * 16 + (lane & 15);
            float m = 0.f;
            #pragma unroll
            for (int mt = 0; mt < 4; ++mt)
                #pragma unroll
                for (int j = 0; j < 4; ++j) {
                    int node = row0 + mt * 16 + rb + j;
                    float v = 0.f;
                    if (node < N_NODES) {
                        v = fmaxf(acc[mt][nt][j] + bv[nt], 0.f) * exists[node];
                        hbf[node * 128 + col] = f2bf(v);
                    }
                    m = fmaxf(m, v);
                }
            m = fmaxf(m, __shfl_xor(m, 16));
            m = fmaxf(m, __shfl_xor(m, 32));
            if ((lane >> 4) == 0)
                atomicMax(pmax + col, __float_as_uint(m));
        }
    }
}

// ---------------- A|B node GEMM: A = h@Wsrc + b (cols 0..127), B = h@Wdst ---
__global__ __launch_bounds__(256)
void gemmAB(const unsigned short* __restrict__ hbf,   // [20000][128]
            const unsigned short* __restrict__ WT,    // [256][128] bf16
            const float* __restrict__ bias,           // [128]
            unsigned short* __restrict__ Abf,         // [20000][128]
            unsigned short* __restrict__ Bbf) {       // [20000][128]
    const int tid  = threadIdx.x;
    const int lane = tid & 63;
    const int wave = tid >> 6;
    const int n0   = wave * 64;
    const int row0 = blockIdx.x * 64;
    const int krow = (lane >> 4) * 8;

    short8 bfrag[4][4];
    {
        int colb = n0 + (lane & 15);
        #pragma unroll
        for (int ks = 0; ks < 4; ++ks)
            #pragma unroll
            for (int nt = 0; nt < 4; ++nt)
                bfrag[ks][nt] = *(const short8*)(WT + (colb + nt * 16) * 128 + ks * 32 + krow);
    }

    f32x4 acc[4][4] = {};
    #pragma unroll
    for (int ks = 0; ks < 4; ++ks)
        #pragma unroll
        for (int mt = 0; mt < 4; ++mt) {
            int row = row0 + mt * 16 + (lane & 15);
            row = min(row, N_NODES - 1);
            short8 a = *(const short8*)(hbf + (size_t)row * 128 + ks * 32 + krow);
            #pragma unroll
            for (int nt = 0; nt < 4; ++nt)
                acc[mt][nt] = __builtin_amdgcn_mfma_f32_16x16x32_bf16(a, bfrag[ks][nt], acc[mt][nt], 0, 0, 0);
        }

    {
        int rb = (lane >> 4) * 4;
        #pragma unroll
        for (int nt = 0; nt < 4; ++nt) {
            int col = n0 + nt * 16 + (lane & 15);        // 0..255
            float badd = (col < 128) ? bias[col] : 0.f;
            #pragma unroll
            for (int mt = 0; mt < 4; ++mt)
                #pragma unroll
                for (int j = 0; j < 4; ++j) {
                    int row = row0 + mt * 16 + rb + j;
                    if (row < N_NODES) {
                        float v = acc[mt][nt][j] + badd;
                        if (col < 128) Abf[(size_t)row * 128 + col] = f2bf(v);
                        else           Bbf[(size_t)row * 128 + col - 128] = f2bf(v);
                    }
                }
        }
    }
}

// ---------------- edge pass: M[s] = max_e (B[dst] + ef@Wef) -----------------
// 16 lanes per edge-chunk; lane owns 8 cols; sorted runs dedup the atomics.
__global__ __launch_bounds__(256)
void edge_pass(const unsigned short* __restrict__ Bbf, // [20000][128]
               const int4* __restrict__ es,            // 2 x int4 per sorted edge
               const float* __restrict__ Wef,          // [12][128] f32 (rows 256..267 of We)
               unsigned* __restrict__ M) {             // [20000][128] encoded, init 0x01..
    const int tid = threadIdx.x;
    const int c   = tid & 15;                 // cols c*8 .. c*8+7
    const int grp = blockIdx.x * 16 + (tid >> 4);
    const size_t e0 = (size_t)grp * L_CHUNK;

    // register-resident W_ef slice: [12][8]
    float wef[12][8];
    #pragma unroll
    for (int k = 0; k < 12; ++k) {
        float4 a = *(const float4*)(Wef + k * 128 + c * 8);
        float4 b = *(const float4*)(Wef + k * 128 + c * 8 + 4);
        wef[k][0] = a.x; wef[k][1] = a.y; wef[k][2] = a.z; wef[k][3] = a.w;
        wef[k][4] = b.x; wef[k][5] = b.y; wef[k][6] = b.z; wef[k][7] = b.w;
    }

    const int4* p = es + 2 * e0;
    int4 r0a = p[0], r0b = p[1];
    int4 r1a = p[2], r1b = p[3];
    int4 r2a = p[4], r2b = p[5];
    short8 b0 = *(const short8*)(Bbf + (size_t)r0a.y * 128 + c * 8);
    short8 b1 = *(const short8*)(Bbf + (size_t)r1a.y * 128 + c * 8);

    int cur = r0a.x;
    float rm[8];
    #pragma unroll
    for (int j = 0; j < 8; ++j) rm[j] = -1e30f;

    for (int i = 0; i < L_CHUNK; ++i) {
        // prefetch record i+3 and B for edge i+2 (reads may touch zero pad)
        int4 r3a = p[2 * i + 6], r3b = p[2 * i + 7];
        short8 b2 = *(const short8*)(Bbf + (size_t)r2a.y * 128 + c * 8);

        // unpack ef (12 bf16) of edge i
        float ef[12];
        {
            unsigned u;
            u = (unsigned)r0a.z; ef[0] = __uint_as_float(u << 16); ef[1] = __uint_as_float(u & 0xFFFF0000u);
            u = (unsigned)r0a.w; ef[2] = __uint_as_float(u << 16); ef[3] = __uint_as_float(u & 0xFFFF0000u);
            u = (unsigned)r0b.x; ef[4] = __uint_as_float(u << 16); ef[5] = __uint_as_float(u & 0xFFFF0000u);
            u = (unsigned)r0b.y; ef[6] = __uint_as_float(u << 16); ef[7] = __uint_as_float(u & 0xFFFF0000u);
            u = (unsigned)r0b.z; ef[8] = __uint_as_float(u << 16); ef[9] = __uint_as_float(u & 0xFFFF0000u);
            u = (unsigned)r0b.w; ef[10] = __uint_as_float(u << 16); ef[11] = __uint_as_float(u & 0xFFFF0000u);
        }

        float msg[8];
        #pragma unroll
        for (int j = 0; j < 8; ++j) {
            float a = bf2f((unsigned short)b0[j]);
            #pragma unroll
            for (int k = 0; k < 12; ++k) a = fmaf(ef[k], wef[k][j], a);
            msg[j] = a;
        }

        if (r0a.x != cur) {                      // uniform within the 16-lane group
            unsigned* mb = M + (size_t)cur * 128 + c * 8;
            #pragma unroll
            for (int j = 0; j < 8; ++j) atomicMax(mb + j, encf(rm[j]));
            #pragma unroll
            for (int j = 0; j < 8; ++j) rm[j] = msg[j];
            cur = r0a.x;
        } else {
            #pragma unroll
            for (int j = 0; j < 8; ++j) rm[j] = fmaxf(rm[j], msg[j]);
        }

        r0a = r1a; r0b = r1b; r1a = r2a; r1b = r2b; r2a = r3a; r2b = r3b;
        b0 = b1; b1 = b2;
    }
    unsigned* mb = M + (size_t)cur * 128 + c * 8;
    #pragma unroll
    for (int j = 0; j < 8; ++j) atomicMax(mb + j, encf(rm[j]));
}

// ---------------- finalize: h = relu(A + M), colmax into parent slice -------
__global__ void finalize(const unsigned short* __restrict__ Abf,
                         const unsigned* __restrict__ M,
                         unsigned short* __restrict__ hbf,
                         unsigned* __restrict__ pslice) {
    int g = blockIdx.x * 256 + threadIdx.x;   // 512 blocks
    int c = g & 127;
    float m = 0.f;
    for (int r = g >> 7; r < N_NODES; r += 1024) {
        float v = fmaxf(bf2f(Abf[(size_t)r * 128 + c]) + decf(M[(size_t)r * 128 + c]), 0.f);
        hbf[(size_t)r * 128 + c] = f2bf(v);
        m = fmaxf(m, v);
    }
    atomicMax(pslice + c, __float_as_uint(m));
}

// ---------------- final: out = relu(parent @ Wp + bp) ----------------------
__global__ void final_gemm(const float* __restrict__ parent,
                           const float* __restrict__ Wp,
                           const float* __restrict__ bp,
                           float* __restrict__ out) {
    __shared__ float p[384];
    int t = threadIdx.x;
    for (int i = t; i < 384; i += 256) p[i] = parent[i];
    __syncthreads();
    float s = bp[t];
    for (int k = 0; k < 384; ++k) s += p[k] * Wp[k * 256 + t];
    out[t] = fmaxf(s, 0.f);
}

// ---------------- launch ----------------------------------------------------
extern "C" void kernel_launch(void* const* d_in, const int* in_sizes, int n_in,
                              void* d_out, int out_size, void* d_ws, size_t ws_size,
                              hipStream_t stream) {
    const float* child_feats  = (const float*)d_in[0];
    const float* child_exists = (const float*)d_in[1];
    const float* onehot       = (const float*)d_in[2];
    const float* efeat        = (const float*)d_in[3];
    const int*   eidx         = (const int*)d_in[4];
    const float* Wc  = (const float*)d_in[5];
    const float* bc  = (const float*)d_in[6];
    const float* We0 = (const float*)d_in[7];
    const float* be0 = (const float*)d_in[8];
    const float* We1 = (const float*)d_in[9];
    const float* be1 = (const float*)d_in[10];
    const float* Wp  = (const float*)d_in[11];
    const float* bp  = (const float*)d_in[12];

    char* ws = (char*)d_ws;
    unsigned short* hbf    = (unsigned short*)(ws);                //  5,120,000
    unsigned*       M      = (unsigned*)(ws + 5120000);            // 10,240,000
    unsigned short* Abf    = (unsigned short*)(ws + 15360000);     //  5,120,000
    unsigned short* Bbf    = (unsigned short*)(ws + 20480000);     //  5,120,000
    int4*           es     = (int4*)(ws + 25600000);               // 20,480,256 (640008 x 32B)
    unsigned short* WcT    = (unsigned short*)(ws + 46080256);     //     81,920
    unsigned short* Wab0   = (unsigned short*)(ws + 46162176);     //     65,536
    unsigned short* Wab1   = (unsigned short*)(ws + 46227712);     //     65,536
    unsigned*       parent = (unsigned*)(ws + 46293248);           //      1,536
    unsigned*       hist   = (unsigned*)(ws + 46294784);           //     80,000
    unsigned*       cursor = (unsigned*)(ws + 46374784);           //     80,000

    const float* Wef0 = We0 + 256 * 128;   // [12][128] rows 256..267
    const float* Wef1 = We1 + 256 * 128;

    hipMemsetAsync(parent, 0, 384 * 4, stream);
    hipMemsetAsync(hist, 0, N_NODES * 4, stream);
    hipMemsetAsync((char*)es + (size_t)N_EDGES * 32, 0, 8 * 32, stream);  // pad records

    prep_weights<<<416, 256, 0, stream>>>(Wc, We0, We1, WcT, Wab0, Wab1);
    hist_kernel<<<2500, 256, 0, stream>>>(eidx, hist);
    scan_kernel<<<1, 1024, 0, stream>>>(hist, cursor);
    scatter_kernel<<<2500, 256, 0, stream>>>(eidx, onehot, efeat, cursor, es);

    child_gemm<<<313, 256, 0, stream>>>(child_feats, child_exists, WcT, bc, hbf, parent);

    // ---- layer 1 ----
    hipMemsetAsync(M, 0x01, (size_t)N_NODES * 128 * 4, stream);   // decodes to -1.7e38
    gemmAB<<<313, 256, 0, stream>>>(hbf, Wab0, be0, Abf, Bbf);
    edge_pass<<<800, 256, 0, stream>>>(Bbf, es, Wef0, M);
    finalize<<<512, 256, 0, stream>>>(Abf, M, hbf, parent + 128);

    // ---- layer 2 ----
    hipMemsetAsync(M, 0x01, (size_t)N_NODES * 128 * 4, stream);
    gemmAB<<<313, 256, 0, stream>>>(hbf, Wab1, be1, Abf, Bbf);
    edge_pass<<<800, 256, 0, stream>>>(Bbf, es, Wef1, M);
    finalize<<<512, 256, 0, stream>>>(Abf, M, hbf, parent + 256);

    final_gemm<<<1, 256, 0, stream>>>((const float*)parent, Wp, bp, (float*)d_out);
}

// Round 4
// 324.381 us; speedup vs baseline: 1.9184x; 1.3445x over previous
//
#include <hip/hip_runtime.h>

// ---------------- problem constants ----------------
#define N_NODES   20000
#define N_EDGES   640000
#define CF        313      // FEAT + NUM_SEM
#define KC        320      // child K padded (313 -> 320), 10 ksteps
#define ROWB      640      // child LDS A-tile row stride bytes

typedef __attribute__((ext_vector_type(8))) short short8;
typedef __attribute__((ext_vector_type(4))) float f32x4;
typedef __attribute__((ext_vector_type(4))) unsigned short u16x4;

static __device__ __forceinline__ unsigned short f2bf(float f) {
    unsigned u = __float_as_uint(f);
    u = u + 0x7FFFu + ((u >> 16) & 1u);   // RNE
    return (unsigned short)(u >> 16);
}
static __device__ __forceinline__ float bflo(unsigned u) { return __uint_as_float(u << 16); }
static __device__ __forceinline__ float bfhi(unsigned u) { return __uint_as_float(u & 0xffff0000u); }
static __device__ __forceinline__ int pkbf(float a, float b) {
    return (int)((unsigned)f2bf(a) | ((unsigned)f2bf(b) << 16));
}

// ---------------- weight prep ----------------
// WcT [128][320] bf16 (child W^T);  Wab [256][128] bf16 per layer:
// row n<128: A-col n uses We[k][n] (Wsrc); row n>=128: B-col uses We[128+k][n-128] (Wdst).
__global__ void prep_weights(const float* __restrict__ Wc,
                             const float* __restrict__ We0,
                             const float* __restrict__ We1,
                             unsigned short* __restrict__ WcT,
                             unsigned short* __restrict__ Wab0,
                             unsigned short* __restrict__ Wab1) {
    int g = blockIdx.x * 256 + threadIdx.x;           // 416*256 = 106496 exactly
    if (g < 128 * KC) {
        int n = g / KC, k = g % KC;
        WcT[g] = f2bf(k < CF ? Wc[k * 128 + n] : 0.f);
    } else if (g < 128 * KC + 32768) {
        int h = g - 128 * KC;
        int n = h >> 7, k = h & 127;
        Wab0[h] = f2bf(n < 128 ? We0[k * 128 + n] : We0[(128 + k) * 128 + (n - 128)]);
    } else {
        int h = g - 128 * KC - 32768;
        int n = h >> 7, k = h & 127;
        Wab1[h] = f2bf(n < 128 ? We1[k * 128 + n] : We1[(128 + k) * 128 + (n - 128)]);
    }
}

// ---------------- counting sort by src ----------------
__global__ void hist_kernel(const int* __restrict__ eidx, unsigned* __restrict__ hist) {
    int e = blockIdx.x * 256 + threadIdx.x;
    if (e < N_EDGES) atomicAdd(hist + eidx[2 * e], 1u);
}

__global__ void scan_kernel(const unsigned* __restrict__ hist,
                            unsigned* __restrict__ cursor,
                            unsigned* __restrict__ cstart) {
    __shared__ unsigned part[1024];
    int t = threadIdx.x;
    unsigned loc[20];
    unsigned s = 0;
    int base = t * 20;
    if (t < 1000) {
        #pragma unroll
        for (int i = 0; i < 20; ++i) { loc[i] = hist[base + i]; s += loc[i]; }
    }
    part[t] = s;
    __syncthreads();
    for (int off = 1; off < 1024; off <<= 1) {
        unsigned u = (t >= off) ? part[t - off] : 0u;
        __syncthreads();
        part[t] += u;
        __syncthreads();
    }
    if (t < 1000) {
        unsigned run = part[t] - s;
        #pragma unroll
        for (int i = 0; i < 20; ++i) {
            cursor[base + i] = run;
            cstart[base + i] = run;
            run += loc[i];
        }
    }
}

// 32B record per sorted edge: {dst, 12 bf16 ef (oh0..3, ef0..7), pad}
__global__ void scatter_kernel(const int* __restrict__ eidx,
                               const float* __restrict__ onehot,
                               const float* __restrict__ efeat,
                               unsigned* __restrict__ cursor,
                               int4* __restrict__ es) {
    int e = blockIdx.x * 256 + threadIdx.x;
    if (e >= N_EDGES) return;
    int2 sd = ((const int2*)eidx)[e];
    unsigned pos = atomicAdd(cursor + sd.x, 1u);
    float4 oh = *(const float4*)(onehot + 4 * (size_t)e);
    float4 ea = *(const float4*)(efeat + 8 * (size_t)e);
    float4 eb = *(const float4*)(efeat + 8 * (size_t)e + 4);
    int4 w0, w1;
    w0.x = sd.y;
    w0.y = pkbf(oh.x, oh.y); w0.z = pkbf(oh.z, oh.w); w0.w = pkbf(ea.x, ea.y);
    w1.x = pkbf(ea.z, ea.w); w1.y = pkbf(eb.x, eb.y); w1.z = pkbf(eb.z, eb.w); w1.w = 0;
    es[2 * (size_t)pos]     = w0;
    es[2 * (size_t)pos + 1] = w1;
}

// ---------------- child encoder: h = relu(cf @ Wc + bc) * exists ------------
__global__ __launch_bounds__(256, 2)
void child_gemm(const float* __restrict__ cf,
                const float* __restrict__ exists,
                const unsigned short* __restrict__ WT,
                const float* __restrict__ bias,
                unsigned short* __restrict__ hbf,
                unsigned int* __restrict__ pmax) {
    __shared__ __align__(16) unsigned char Alds[64 * ROWB];

    const int tid  = threadIdx.x;
    const int lane = tid & 63;
    const int wave = tid >> 6;
    const int n0   = wave * 32;
    const int row0 = blockIdx.x * 64;

    short8 bfrag[10][2];
    {
        int col  = n0 + (lane & 15);
        int krow = (lane >> 4) * 8;
        #pragma unroll
        for (int ks = 0; ks < 10; ++ks)
            #pragma unroll
            for (int nt = 0; nt < 2; ++nt)
                bfrag[ks][nt] = *(const short8*)(WT + (col + nt * 16) * KC + ks * 32 + krow);
    }
    float bv[2];
    bv[0] = bias[n0 + (lane & 15)];
    bv[1] = bias[n0 + 16 + (lane & 15)];

    {
        int r = tid >> 2, p = tid & 3;
        int node = row0 + r;
        bool valid = node < N_NODES;
        const float* g = cf + (size_t)node * CF;
        unsigned rbase = r * ROWB;
        unsigned sw = (r & 7) << 4;
        #pragma unroll
        for (int i = 0; i < 10; ++i) {
            int c = p + i * 4;
            short8 v = {};
            if (valid) {
                #pragma unroll
                for (int kk = 0; kk < 8; ++kk) {
                    int k = c * 8 + kk;
                    if (k < CF) v[kk] = (short)f2bf(g[k]);
                }
            }
            *(short8*)(Alds + ((rbase + c * 16) ^ sw)) = v;
        }
    }
    __syncthreads();

    f32x4 acc[4][2] = {};
    {
        int arow = lane & 15;
        unsigned kb = (lane >> 4) * 16;
        #pragma unroll
        for (int ks = 0; ks < 10; ++ks)
            #pragma unroll
            for (int mt = 0; mt < 4; ++mt) {
                int row = mt * 16 + arow;
                short8 a = *(const short8*)(Alds + (((unsigned)row * ROWB + ks * 64 + kb) ^ ((row & 7) << 4)));
                acc[mt][0] = __builtin_amdgcn_mfma_f32_16x16x32_bf16(a, bfrag[ks][0], acc[mt][0], 0, 0, 0);
                acc[mt][1] = __builtin_amdgcn_mfma_f32_16x16x32_bf16(a, bfrag[ks][1], acc[mt][1], 0, 0, 0);
            }
    }

    {
        int rb = (lane >> 4) * 4;
        #pragma unroll
        for (int nt = 0; nt < 2; ++nt) {
            int col = n0 + nt * 16 + (lane & 15);
            float m = 0.f;
            #pragma unroll
            for (int mt = 0; mt < 4; ++mt)
                #pragma unroll
                for (int j = 0; j < 4; ++j) {
                    int node = row0 + mt * 16 + rb + j;
                    float v = 0.f;
                    if (node < N_NODES) {
                        v = fmaxf(acc[mt][nt][j] + bv[nt], 0.f) * exists[node];
                        hbf[node * 128 + col] = f2bf(v);
                    }
                    m = fmaxf(m, v);
                }
            m = fmaxf(m, __shfl_xor(m, 16));
            m = fmaxf(m, __shfl_xor(m, 32));
            if ((lane >> 4) == 0)
                atomicMax(pmax + col, __float_as_uint(m));
        }
    }
}

// ---------------- A|B node GEMM: A = h@Wsrc + b (f32), B = h@Wdst (bf16) ----
__global__ __launch_bounds__(256)
void gemmAB(const unsigned short* __restrict__ hbf,   // [20000][128]
            const unsigned short* __restrict__ WT,    // [256][128] bf16
            const float* __restrict__ bias,           // [128]
            float* __restrict__ Afl,                  // [20000][128] f32
            unsigned short* __restrict__ Bbf) {       // [20000][128] bf16
    const int tid  = threadIdx.x;
    const int lane = tid & 63;
    const int wave = tid >> 6;
    const int n0   = wave * 64;
    const int row0 = blockIdx.x * 64;
    const int krow = (lane >> 4) * 8;

    short8 bfrag[4][4];
    {
        int colb = n0 + (lane & 15);
        #pragma unroll
        for (int ks = 0; ks < 4; ++ks)
            #pragma unroll
            for (int nt = 0; nt < 4; ++nt)
                bfrag[ks][nt] = *(const short8*)(WT + (colb + nt * 16) * 128 + ks * 32 + krow);
    }

    f32x4 acc[4][4] = {};
    #pragma unroll
    for (int ks = 0; ks < 4; ++ks)
        #pragma unroll
        for (int mt = 0; mt < 4; ++mt) {
            int row = row0 + mt * 16 + (lane & 15);
            row = min(row, N_NODES - 1);
            short8 a = *(const short8*)(hbf + (size_t)row * 128 + ks * 32 + krow);
            #pragma unroll
            for (int nt = 0; nt < 4; ++nt)
                acc[mt][nt] = __builtin_amdgcn_mfma_f32_16x16x32_bf16(a, bfrag[ks][nt], acc[mt][nt], 0, 0, 0);
        }

    {
        int rb = (lane >> 4) * 4;
        #pragma unroll
        for (int nt = 0; nt < 4; ++nt) {
            int col = n0 + nt * 16 + (lane & 15);        // 0..255
            float badd = (col < 128) ? bias[col] : 0.f;
            #pragma unroll
            for (int mt = 0; mt < 4; ++mt)
                #pragma unroll
                for (int j = 0; j < 4; ++j) {
                    int row = row0 + mt * 16 + rb + j;
                    if (row < N_NODES) {
                        float v = acc[mt][nt][j] + badd;
                        if (col < 128) Afl[(size_t)row * 128 + col] = v;
                        else           Bbf[(size_t)row * 128 + col - 128] = f2bf(v);
                    }
                }
        }
    }
}

// ---------------- edge pass (fused finalize): one 32-lane group per src -----
// h[s] = relu(A[s] + max_e(B[dst_e] + ef_e @ Wef)); plain store, no M array.
__global__ __launch_bounds__(512)
void edge_pass(const unsigned short* __restrict__ Bbf, // [20000][128] bf16
               const float* __restrict__ Afl,          // [20000][128] f32
               const int4* __restrict__ es,            // 2 x int4 per sorted edge
               const float* __restrict__ Wef,          // [12][128] f32 (We rows 256..267)
               const unsigned* __restrict__ cstart,    // [20000] seg start
               const unsigned* __restrict__ hist,      // [20000] seg count
               unsigned short* __restrict__ hbf,       // [20000][128] bf16 out
               unsigned* __restrict__ pslice) {        // [128] colmax (f32 bits)
    __shared__ unsigned cmax[128];
    const int tid = threadIdx.x;
    if (tid < 128) cmax[tid] = 0;
    __syncthreads();

    const int s  = blockIdx.x * 16 + (tid >> 5);   // 1250*16 = 20000 exactly
    const int c0 = (tid & 31) * 4;                  // 4 cols per lane

    float4 wf[12];
    #pragma unroll
    for (int k = 0; k < 12; ++k) wf[k] = *(const float4*)(Wef + k * 128 + c0);

    float m0 = -1e30f, m1 = -1e30f, m2 = -1e30f, m3 = -1e30f;
    const unsigned cnt = hist[s];
    if (cnt) {
        const int4* p = es + 2 * (size_t)cstart[s];
        const unsigned last = cnt - 1;
        int4 ra0 = p[0], rb0 = p[1];
        unsigned j1 = min(1u, last), j2 = min(2u, last);
        int4 ra1 = p[2 * j1], rb1 = p[2 * j1 + 1];
        int4 ra2 = p[2 * j2], rb2 = p[2 * j2 + 1];
        u16x4 b0 = *(const u16x4*)(Bbf + (size_t)(unsigned)ra0.x * 128 + c0);
        u16x4 b1 = *(const u16x4*)(Bbf + (size_t)(unsigned)ra1.x * 128 + c0);
        #pragma unroll 4
        for (unsigned i = 0; i < cnt; ++i) {
            u16x4 b2 = *(const u16x4*)(Bbf + (size_t)(unsigned)ra2.x * 128 + c0);
            unsigned j3 = min(i + 3, last);
            int4 ra3 = p[2 * j3], rb3 = p[2 * j3 + 1];

            float ef[12];
            unsigned u;
            u = (unsigned)ra0.y; ef[0] = bflo(u);  ef[1] = bfhi(u);
            u = (unsigned)ra0.z; ef[2] = bflo(u);  ef[3] = bfhi(u);
            u = (unsigned)ra0.w; ef[4] = bflo(u);  ef[5] = bfhi(u);
            u = (unsigned)rb0.x; ef[6] = bflo(u);  ef[7] = bfhi(u);
            u = (unsigned)rb0.y; ef[8] = bflo(u);  ef[9] = bfhi(u);
            u = (unsigned)rb0.z; ef[10] = bflo(u); ef[11] = bfhi(u);

            float x0 = bflo((unsigned)(unsigned short)b0[0] << 0 | 0u), x1, x2, x3;
            // (re-expand cleanly)
            x0 = __uint_as_float(((unsigned)(unsigned short)b0[0]) << 16);
            x1 = __uint_as_float(((unsigned)(unsigned short)b0[1]) << 16);
            x2 = __uint_as_float(((unsigned)(unsigned short)b0[2]) << 16);
            x3 = __uint_as_float(((unsigned)(unsigned short)b0[3]) << 16);
            #pragma unroll
            for (int k = 0; k < 12; ++k) {
                x0 = fmaf(ef[k], wf[k].x, x0);
                x1 = fmaf(ef[k], wf[k].y, x1);
                x2 = fmaf(ef[k], wf[k].z, x2);
                x3 = fmaf(ef[k], wf[k].w, x3);
            }
            m0 = fmaxf(m0, x0); m1 = fmaxf(m1, x1);
            m2 = fmaxf(m2, x2); m3 = fmaxf(m3, x3);

            ra0 = ra1; rb0 = rb1; ra1 = ra2; rb1 = rb2; ra2 = ra3; rb2 = rb3;
            b0 = b1; b1 = b2;
        }
    }

    float4 a = *(const float4*)(Afl + (size_t)s * 128 + c0);
    float h0 = fmaxf(a.x + m0, 0.f), h1 = fmaxf(a.y + m1, 0.f);
    float h2 = fmaxf(a.z + m2, 0.f), h3 = fmaxf(a.w + m3, 0.f);

    unsigned lo = (unsigned)f2bf(h0) | ((unsigned)f2bf(h1) << 16);
    unsigned hi = (unsigned)f2bf(h2) | ((unsigned)f2bf(h3) << 16);
    *(uint2*)(hbf + (size_t)s * 128 + c0) = make_uint2(lo, hi);

    // colmax: reduce the two srcs of this wave, then LDS, then global
    float g0 = fmaxf(h0, __shfl_xor(h0, 32));
    float g1 = fmaxf(h1, __shfl_xor(h1, 32));
    float g2 = fmaxf(h2, __shfl_xor(h2, 32));
    float g3 = fmaxf(h3, __shfl_xor(h3, 32));
    if ((tid & 63) < 32) {
        atomicMax(&cmax[c0],     __float_as_uint(g0));
        atomicMax(&cmax[c0 + 1], __float_as_uint(g1));
        atomicMax(&cmax[c0 + 2], __float_as_uint(g2));
        atomicMax(&cmax[c0 + 3], __float_as_uint(g3));
    }
    __syncthreads();
    if (tid < 128) atomicMax(pslice + tid, cmax[tid]);
}

// ---------------- final: out = relu(parent @ Wp + bp) ----------------------
__global__ void final_gemm(const float* __restrict__ parent,
                           const float* __restrict__ Wp,
                           const float* __restrict__ bp,
                           float* __restrict__ out) {
    __shared__ float p[384];
    int t = threadIdx.x;
    for (int i = t; i < 384; i += 256) p[i] = parent[i];
    __syncthreads();
    float s = bp[t];
    for (int k = 0; k < 384; ++k) s += p[k] * Wp[k * 256 + t];
    out[t] = fmaxf(s, 0.f);
}

// ---------------- launch ----------------------------------------------------
extern "C" void kernel_launch(void* const* d_in, const int* in_sizes, int n_in,
                              void* d_out, int out_size, void* d_ws, size_t ws_size,
                              hipStream_t stream) {
    const float* child_feats  = (const float*)d_in[0];
    const float* child_exists = (const float*)d_in[1];
    const float* onehot       = (const float*)d_in[2];
    const float* efeat        = (const float*)d_in[3];
    const int*   eidx         = (const int*)d_in[4];
    const float* Wc  = (const float*)d_in[5];
    const float* bc  = (const float*)d_in[6];
    const float* We0 = (const float*)d_in[7];
    const float* be0 = (const float*)d_in[8];
    const float* We1 = (const float*)d_in[9];
    const float* be1 = (const float*)d_in[10];
    const float* Wp  = (const float*)d_in[11];
    const float* bp  = (const float*)d_in[12];

    char* ws = (char*)d_ws;
    unsigned short* hbf    = (unsigned short*)(ws);                //  5,120,000
    float*          Afl    = (float*)(ws + 5120000);               // 10,240,000
    unsigned short* Bbf    = (unsigned short*)(ws + 15360000);     //  5,120,000
    int4*           es     = (int4*)(ws + 20480000);               // 20,480,000
    unsigned short* WcT    = (unsigned short*)(ws + 40960000);     //     81,920
    unsigned short* Wab0   = (unsigned short*)(ws + 41041920);     //     65,536
    unsigned short* Wab1   = (unsigned short*)(ws + 41107456);     //     65,536
    unsigned*       parent = (unsigned*)(ws + 41172992);           //      1,536
    unsigned*       hist   = (unsigned*)(ws + 41174528);           //     80,000
    unsigned*       cstart = (unsigned*)(ws + 41254528);           //     80,000
    unsigned*       cursor = (unsigned*)(ws + 41334528);           //     80,000

    const float* Wef0 = We0 + 256 * 128;   // [12][128] rows 256..267
    const float* Wef1 = We1 + 256 * 128;

    hipMemsetAsync(parent, 0, 384 * 4, stream);
    hipMemsetAsync(hist, 0, N_NODES * 4, stream);

    prep_weights<<<416, 256, 0, stream>>>(Wc, We0, We1, WcT, Wab0, Wab1);
    hist_kernel<<<2500, 256, 0, stream>>>(eidx, hist);
    scan_kernel<<<1, 1024, 0, stream>>>(hist, cursor, cstart);
    scatter_kernel<<<2500, 256, 0, stream>>>(eidx, onehot, efeat, cursor, es);

    child_gemm<<<313, 256, 0, stream>>>(child_feats, child_exists, WcT, bc, hbf, parent);

    // ---- layer 1 ----
    gemmAB<<<313, 256, 0, stream>>>(hbf, Wab0, be0, Afl, Bbf);
    edge_pass<<<1250, 512, 0, stream>>>(Bbf, Afl, es, Wef0, cstart, hist, hbf, parent + 128);

    // ---- layer 2 ----
    gemmAB<<<313, 256, 0, stream>>>(hbf, Wab1, be1, Afl, Bbf);
    edge_pass<<<1250, 512, 0, stream>>>(Bbf, Afl, es, Wef1, cstart, hist, hbf, parent + 256);

    final_gemm<<<1, 256, 0, stream>>>((const float*)parent, Wp, bp, (float*)d_out);
}

// Round 5
// 295.360 us; speedup vs baseline: 2.1069x; 1.0983x over previous
//
#include <hip/hip_runtime.h>

// ---------------- problem constants ----------------
#define N_NODES   20000
#define N_EDGES   640000
#define CF        313      // FEAT + NUM_SEM
#define KC        320      // child K padded (313 -> 320), 10 ksteps
#define ROWB      640      // child LDS A-tile row stride bytes

typedef __attribute__((ext_vector_type(8))) short short8;
typedef __attribute__((ext_vector_type(4))) float f32x4;
typedef __attribute__((ext_vector_type(4))) unsigned short u16x4;
typedef _Float16 h2 __attribute__((ext_vector_type(2)));

static __device__ __forceinline__ unsigned short f2bf(float f) {
    unsigned u = __float_as_uint(f);
    u = u + 0x7FFFu + ((u >> 16) & 1u);   // RNE
    return (unsigned short)(u >> 16);
}
static __device__ __forceinline__ int pkh(float a, float b) {
    h2 h; h.x = (_Float16)a; h.y = (_Float16)b;
    return __builtin_bit_cast(int, h);
}
static __device__ __forceinline__ h2 bch(int v) { return __builtin_bit_cast(h2, v); }
static __device__ __forceinline__ float dot2f(h2 a, h2 b, float c) {
    return __builtin_amdgcn_fdot2(a, b, c, false);   // v_dot2_f32_f16
}

// ---------------- fused setup: weight prep | edge hist | cf -> padded bf16 --
// blocks [0,416): prep; [416,2916): hist; [2916,6041): cf convert
__global__ void setup_kernel(const float* __restrict__ Wc,
                             const float* __restrict__ We0,
                             const float* __restrict__ We1,
                             const int* __restrict__ eidx,
                             const float* __restrict__ cf,
                             unsigned short* __restrict__ WcT,
                             unsigned short* __restrict__ Wab0,
                             unsigned short* __restrict__ Wab1,
                             unsigned* __restrict__ hist,
                             unsigned short* __restrict__ cfp) {
    const int b = blockIdx.x, tid = threadIdx.x;
    if (b < 416) {
        int g = b * 256 + tid;                    // 106496 = 416*256
        if (g < 128 * KC) {
            int n = g / KC, k = g % KC;
            WcT[g] = f2bf(k < CF ? Wc[k * 128 + n] : 0.f);
        } else if (g < 128 * KC + 32768) {
            int h = g - 128 * KC;
            int n = h >> 7, k = h & 127;
            Wab0[h] = f2bf(n < 128 ? We0[k * 128 + n] : We0[(128 + k) * 128 + (n - 128)]);
        } else {
            int h = g - 128 * KC - 32768;
            int n = h >> 7, k = h & 127;
            Wab1[h] = f2bf(n < 128 ? We1[k * 128 + n] : We1[(128 + k) * 128 + (n - 128)]);
        }
    } else if (b < 2916) {
        int e = (b - 416) * 256 + tid;
        if (e < N_EDGES) atomicAdd(hist + eidx[2 * e], 1u);
    } else {
        int g = (b - 2916) * 256 + tid;           // 800000 = 3125*256
        if (g < 800000) {
            int node = g / 40, c = g - node * 40;
            const float* base = cf + (size_t)node * CF;
            short8 v = {};
            #pragma unroll
            for (int kk = 0; kk < 8; ++kk) {
                int k = c * 8 + kk;
                if (k < CF) v[kk] = (short)f2bf(base[k]);
            }
            *(short8*)(cfp + (size_t)g * 8) = v;
        }
    }
}

// ---------------- scan (exclusive prefix over 20000 counts) ----------------
__global__ void scan_kernel(const unsigned* __restrict__ hist,
                            unsigned* __restrict__ cursor,
                            unsigned* __restrict__ cstart) {
    __shared__ unsigned part[1024];
    int t = threadIdx.x;
    unsigned loc[20];
    unsigned s = 0;
    int base = t * 20;
    if (t < 1000) {
        #pragma unroll
        for (int i = 0; i < 20; ++i) { loc[i] = hist[base + i]; s += loc[i]; }
    }
    part[t] = s;
    __syncthreads();
    for (int off = 1; off < 1024; off <<= 1) {
        unsigned u = (t >= off) ? part[t - off] : 0u;
        __syncthreads();
        part[t] += u;
        __syncthreads();
    }
    if (t < 1000) {
        unsigned run = part[t] - s;
        #pragma unroll
        for (int i = 0; i < 20; ++i) {
            cursor[base + i] = run;
            cstart[base + i] = run;
            run += loc[i];
        }
    }
}

// 32B record per sorted edge: {dst, 12 f16 (oh0..3, ef0..7), pad}
__global__ void scatter_kernel(const int* __restrict__ eidx,
                               const float* __restrict__ onehot,
                               const float* __restrict__ efeat,
                               unsigned* __restrict__ cursor,
                               int4* __restrict__ es) {
    int e = blockIdx.x * 256 + threadIdx.x;
    if (e >= N_EDGES) return;
    int2 sd = ((const int2*)eidx)[e];
    unsigned pos = atomicAdd(cursor + sd.x, 1u);
    float4 oh = *(const float4*)(onehot + 4 * (size_t)e);
    float4 ea = *(const float4*)(efeat + 8 * (size_t)e);
    float4 eb = *(const float4*)(efeat + 8 * (size_t)e + 4);
    int4 w0, w1;
    w0.x = sd.y;
    w0.y = pkh(oh.x, oh.y); w0.z = pkh(oh.z, oh.w); w0.w = pkh(ea.x, ea.y);
    w1.x = pkh(ea.z, ea.w); w1.y = pkh(eb.x, eb.y); w1.z = pkh(eb.z, eb.w); w1.w = 0;
    es[2 * (size_t)pos]     = w0;
    es[2 * (size_t)pos + 1] = w1;
}

// ---------------- child encoder: h = relu(cfp @ Wc + bc) * exists ----------
__global__ __launch_bounds__(256, 2)
void child_gemm(const unsigned short* __restrict__ cfp,   // [20000][320] bf16
                const float* __restrict__ exists,
                const unsigned short* __restrict__ WT,    // [128][320] bf16
                const float* __restrict__ bias,
                unsigned short* __restrict__ hbf,
                unsigned int* __restrict__ pmax) {
    __shared__ __align__(16) unsigned char Alds[64 * ROWB];

    const int tid  = threadIdx.x;
    const int lane = tid & 63;
    const int wave = tid >> 6;
    const int n0   = wave * 32;
    const int row0 = blockIdx.x * 64;

    short8 bfrag[10][2];
    {
        int col  = n0 + (lane & 15);
        int krow = (lane >> 4) * 8;
        #pragma unroll
        for (int ks = 0; ks < 10; ++ks)
            #pragma unroll
            for (int nt = 0; nt < 2; ++nt)
                bfrag[ks][nt] = *(const short8*)(WT + (col + nt * 16) * KC + ks * 32 + krow);
    }
    float bv[2];
    bv[0] = bias[n0 + (lane & 15)];
    bv[1] = bias[n0 + 16 + (lane & 15)];

    {
        int r = tid >> 2, p = tid & 3;
        int node = row0 + r;
        bool valid = node < N_NODES;
        unsigned rbase = r * ROWB;
        unsigned sw = (r & 7) << 4;
        #pragma unroll
        for (int i = 0; i < 10; ++i) {
            int c = p + i * 4;
            short8 v = {};
            if (valid) v = *(const short8*)(cfp + (size_t)node * KC + c * 8);
            *(short8*)(Alds + ((rbase + c * 16) ^ sw)) = v;
        }
    }
    __syncthreads();

    f32x4 acc[4][2] = {};
    {
        int arow = lane & 15;
        unsigned kb = (lane >> 4) * 16;
        #pragma unroll
        for (int ks = 0; ks < 10; ++ks)
            #pragma unroll
            for (int mt = 0; mt < 4; ++mt) {
                int row = mt * 16 + arow;
                short8 a = *(const short8*)(Alds + (((unsigned)row * ROWB + ks * 64 + kb) ^ ((row & 7) << 4)));
                acc[mt][0] = __builtin_amdgcn_mfma_f32_16x16x32_bf16(a, bfrag[ks][0], acc[mt][0], 0, 0, 0);
                acc[mt][1] = __builtin_amdgcn_mfma_f32_16x16x32_bf16(a, bfrag[ks][1], acc[mt][1], 0, 0, 0);
            }
    }

    {
        int rb = (lane >> 4) * 4;
        #pragma unroll
        for (int nt = 0; nt < 2; ++nt) {
            int col = n0 + nt * 16 + (lane & 15);
            float m = 0.f;
            #pragma unroll
            for (int mt = 0; mt < 4; ++mt)
                #pragma unroll
                for (int j = 0; j < 4; ++j) {
                    int node = row0 + mt * 16 + rb + j;
                    float v = 0.f;
                    if (node < N_NODES) {
                        v = fmaxf(acc[mt][nt][j] + bv[nt], 0.f) * exists[node];
                        hbf[node * 128 + col] = f2bf(v);
                    }
                    m = fmaxf(m, v);
                }
            m = fmaxf(m, __shfl_xor(m, 16));
            m = fmaxf(m, __shfl_xor(m, 32));
            if ((lane >> 4) == 0)
                atomicMax(pmax + col, __float_as_uint(m));
        }
    }
}

// ---------------- A|B node GEMM: A = h@Wsrc + b (f32), B = h@Wdst (bf16) ----
__global__ __launch_bounds__(256)
void gemmAB(const unsigned short* __restrict__ hbf,
            const unsigned short* __restrict__ WT,    // [256][128] bf16
            const float* __restrict__ bias,
            float* __restrict__ Afl,
            unsigned short* __restrict__ Bbf) {
    const int tid  = threadIdx.x;
    const int lane = tid & 63;
    const int wave = tid >> 6;
    const int n0   = wave * 64;
    const int row0 = blockIdx.x * 64;
    const int krow = (lane >> 4) * 8;

    short8 bfrag[4][4];
    {
        int colb = n0 + (lane & 15);
        #pragma unroll
        for (int ks = 0; ks < 4; ++ks)
            #pragma unroll
            for (int nt = 0; nt < 4; ++nt)
                bfrag[ks][nt] = *(const short8*)(WT + (colb + nt * 16) * 128 + ks * 32 + krow);
    }

    f32x4 acc[4][4] = {};
    #pragma unroll
    for (int ks = 0; ks < 4; ++ks)
        #pragma unroll
        for (int mt = 0; mt < 4; ++mt) {
            int row = row0 + mt * 16 + (lane & 15);
            row = min(row, N_NODES - 1);
            short8 a = *(const short8*)(hbf + (size_t)row * 128 + ks * 32 + krow);
            #pragma unroll
            for (int nt = 0; nt < 4; ++nt)
                acc[mt][nt] = __builtin_amdgcn_mfma_f32_16x16x32_bf16(a, bfrag[ks][nt], acc[mt][nt], 0, 0, 0);
        }

    {
        int rb = (lane >> 4) * 4;
        #pragma unroll
        for (int nt = 0; nt < 4; ++nt) {
            int col = n0 + nt * 16 + (lane & 15);
            float badd = (col < 128) ? bias[col] : 0.f;
            #pragma unroll
            for (int mt = 0; mt < 4; ++mt)
                #pragma unroll
                for (int j = 0; j < 4; ++j) {
                    int row = row0 + mt * 16 + rb + j;
                    if (row < N_NODES) {
                        float v = acc[mt][nt][j] + badd;
                        if (col < 128) Afl[(size_t)row * 128 + col] = v;
                        else           Bbf[(size_t)row * 128 + col - 128] = f2bf(v);
                    }
                }
        }
    }
}

// ---------------- edge pass: h[s] = relu(A[s] + max_e(B[dst]+ef@Wef)) -------
// one 32-lane group per src, 4 cols/lane, v_dot2_f32_f16 inner product
__global__ __launch_bounds__(256)
void edge_pass(const unsigned short* __restrict__ Bbf,
               const float* __restrict__ Afl,
               const int4* __restrict__ es,
               const float* __restrict__ Wef,          // [12][128] f32
               const unsigned* __restrict__ cstart,
               const unsigned* __restrict__ hist,
               unsigned short* __restrict__ hbf,
               unsigned* __restrict__ pslice) {
    __shared__ unsigned cmax[128];
    const int tid = threadIdx.x;
    if (tid < 128) cmax[tid] = 0;
    __syncthreads();

    const int s  = blockIdx.x * 8 + (tid >> 5);   // 2500*8 = 20000
    const int c0 = (tid & 31) * 4;

    h2 wf[6][4];
    #pragma unroll
    for (int kp = 0; kp < 6; ++kp)
        #pragma unroll
        for (int j = 0; j < 4; ++j) {
            h2 w;
            w.x = (_Float16)Wef[(2 * kp) * 128 + c0 + j];
            w.y = (_Float16)Wef[(2 * kp + 1) * 128 + c0 + j];
            wf[kp][j] = w;
        }

    float m0 = -1e30f, m1 = -1e30f, m2 = -1e30f, m3 = -1e30f;
    const unsigned cnt = hist[s];
    if (cnt) {
        const int4* p = es + 2 * (size_t)cstart[s];
        const unsigned last = cnt - 1;
        unsigned j1 = min(1u, last), j2 = min(2u, last), j3 = min(3u, last);
        int4 ra0 = p[0],      rb0 = p[1];
        int4 ra1 = p[2 * j1], rb1 = p[2 * j1 + 1];
        int4 ra2 = p[2 * j2], rb2 = p[2 * j2 + 1];
        int4 ra3 = p[2 * j3], rb3 = p[2 * j3 + 1];
        u16x4 b0 = *(const u16x4*)(Bbf + (size_t)(unsigned)ra0.x * 128 + c0);
        u16x4 b1 = *(const u16x4*)(Bbf + (size_t)(unsigned)ra1.x * 128 + c0);
        u16x4 b2 = *(const u16x4*)(Bbf + (size_t)(unsigned)ra2.x * 128 + c0);
        #pragma unroll 4
        for (unsigned i = 0; i < cnt; ++i) {
            u16x4 b3 = *(const u16x4*)(Bbf + (size_t)(unsigned)ra3.x * 128 + c0);
            unsigned j4 = min(i + 4, last);
            int4 ra4 = p[2 * j4], rb4 = p[2 * j4 + 1];

            h2 e0 = bch(ra0.y), e1 = bch(ra0.z), e2 = bch(ra0.w);
            h2 e3 = bch(rb0.x), e4 = bch(rb0.y), e5 = bch(rb0.z);

            float x0 = __uint_as_float(((unsigned)(unsigned short)b0[0]) << 16);
            float x1 = __uint_as_float(((unsigned)(unsigned short)b0[1]) << 16);
            float x2 = __uint_as_float(((unsigned)(unsigned short)b0[2]) << 16);
            float x3 = __uint_as_float(((unsigned)(unsigned short)b0[3]) << 16);
            x0 = dot2f(e0, wf[0][0], x0); x1 = dot2f(e0, wf[0][1], x1);
            x2 = dot2f(e0, wf[0][2], x2); x3 = dot2f(e0, wf[0][3], x3);
            x0 = dot2f(e1, wf[1][0], x0); x1 = dot2f(e1, wf[1][1], x1);
            x2 = dot2f(e1, wf[1][2], x2); x3 = dot2f(e1, wf[1][3], x3);
            x0 = dot2f(e2, wf[2][0], x0); x1 = dot2f(e2, wf[2][1], x1);
            x2 = dot2f(e2, wf[2][2], x2); x3 = dot2f(e2, wf[2][3], x3);
            x0 = dot2f(e3, wf[3][0], x0); x1 = dot2f(e3, wf[3][1], x1);
            x2 = dot2f(e3, wf[3][2], x2); x3 = dot2f(e3, wf[3][3], x3);
            x0 = dot2f(e4, wf[4][0], x0); x1 = dot2f(e4, wf[4][1], x1);
            x2 = dot2f(e4, wf[4][2], x2); x3 = dot2f(e4, wf[4][3], x3);
            x0 = dot2f(e5, wf[5][0], x0); x1 = dot2f(e5, wf[5][1], x1);
            x2 = dot2f(e5, wf[5][2], x2); x3 = dot2f(e5, wf[5][3], x3);
            m0 = fmaxf(m0, x0); m1 = fmaxf(m1, x1);
            m2 = fmaxf(m2, x2); m3 = fmaxf(m3, x3);

            ra0 = ra1; rb0 = rb1; ra1 = ra2; rb1 = rb2;
            ra2 = ra3; rb2 = rb3; ra3 = ra4; rb3 = rb4;
            b0 = b1; b1 = b2; b2 = b3;
        }
    }

    float4 a = *(const float4*)(Afl + (size_t)s * 128 + c0);
    float h0 = fmaxf(a.x + m0, 0.f), h1 = fmaxf(a.y + m1, 0.f);
    float h2v = fmaxf(a.z + m2, 0.f), h3 = fmaxf(a.w + m3, 0.f);

    unsigned lo = (unsigned)f2bf(h0) | ((unsigned)f2bf(h1) << 16);
    unsigned hi = (unsigned)f2bf(h2v) | ((unsigned)f2bf(h3) << 16);
    *(uint2*)(hbf + (size_t)s * 128 + c0) = make_uint2(lo, hi);

    float g0 = fmaxf(h0, __shfl_xor(h0, 32));
    float g1 = fmaxf(h1, __shfl_xor(h1, 32));
    float g2 = fmaxf(h2v, __shfl_xor(h2v, 32));
    float g3 = fmaxf(h3, __shfl_xor(h3, 32));
    if ((tid & 63) < 32) {
        atomicMax(&cmax[c0],     __float_as_uint(g0));
        atomicMax(&cmax[c0 + 1], __float_as_uint(g1));
        atomicMax(&cmax[c0 + 2], __float_as_uint(g2));
        atomicMax(&cmax[c0 + 3], __float_as_uint(g3));
    }
    __syncthreads();
    if (tid < 128) atomicMax(pslice + tid, cmax[tid]);
}

// ---------------- final: out = relu(parent @ Wp + bp), K split x4 ----------
__global__ void final_gemm(const float* __restrict__ parent,
                           const float* __restrict__ Wp,
                           const float* __restrict__ bp,
                           float* __restrict__ out) {
    __shared__ float p[384];
    __shared__ float red[1024];
    int t = threadIdx.x;
    if (t < 384) p[t] = parent[t];
    __syncthreads();
    int col = t & 255, kc = t >> 8;
    float s = 0.f;
    for (int k = kc * 96; k < kc * 96 + 96; ++k) s += p[k] * Wp[k * 256 + col];
    red[t] = s;
    __syncthreads();
    if (kc == 0)
        out[col] = fmaxf(red[col] + red[col + 256] + red[col + 512] + red[col + 768] + bp[col], 0.f);
}

// ---------------- launch ----------------------------------------------------
extern "C" void kernel_launch(void* const* d_in, const int* in_sizes, int n_in,
                              void* d_out, int out_size, void* d_ws, size_t ws_size,
                              hipStream_t stream) {
    const float* child_feats  = (const float*)d_in[0];
    const float* child_exists = (const float*)d_in[1];
    const float* onehot       = (const float*)d_in[2];
    const float* efeat        = (const float*)d_in[3];
    const int*   eidx         = (const int*)d_in[4];
    const float* Wc  = (const float*)d_in[5];
    const float* bc  = (const float*)d_in[6];
    const float* We0 = (const float*)d_in[7];
    const float* be0 = (const float*)d_in[8];
    const float* We1 = (const float*)d_in[9];
    const float* be1 = (const float*)d_in[10];
    const float* Wp  = (const float*)d_in[11];
    const float* bp  = (const float*)d_in[12];

    char* ws = (char*)d_ws;
    unsigned short* hbf    = (unsigned short*)(ws);                //  5,120,000
    float*          Afl    = (float*)(ws + 5120000);               // 10,240,000
    unsigned short* Bbf    = (unsigned short*)(ws + 15360000);     //  5,120,000
    int4*           es     = (int4*)(ws + 20480000);               // 20,480,000
    unsigned short* cfp    = (unsigned short*)(ws + 40960000);     // 12,800,000
    unsigned short* WcT    = (unsigned short*)(ws + 53760000);     //     81,920
    unsigned short* Wab0   = (unsigned short*)(ws + 53841920);     //     65,536
    unsigned short* Wab1   = (unsigned short*)(ws + 53907456);     //     65,536
    unsigned*       parent = (unsigned*)(ws + 53972992);           //      1,536
    unsigned*       hist   = (unsigned*)(ws + 53974528);           //     80,000
    unsigned*       cstart = (unsigned*)(ws + 54054528);           //     80,000
    unsigned*       cursor = (unsigned*)(ws + 54134528);           //     80,000

    const float* Wef0 = We0 + 256 * 128;   // [12][128] rows 256..267
    const float* Wef1 = We1 + 256 * 128;

    hipMemsetAsync(parent, 0, 384 * 4, stream);
    hipMemsetAsync(hist, 0, N_NODES * 4, stream);

    setup_kernel<<<6041, 256, 0, stream>>>(Wc, We0, We1, eidx, child_feats,
                                           WcT, Wab0, Wab1, hist, cfp);
    scan_kernel<<<1, 1024, 0, stream>>>(hist, cursor, cstart);
    child_gemm<<<313, 256, 0, stream>>>(cfp, child_exists, WcT, bc, hbf, parent);
    scatter_kernel<<<2500, 256, 0, stream>>>(eidx, onehot, efeat, cursor, es);

    // ---- layer 1 ----
    gemmAB<<<313, 256, 0, stream>>>(hbf, Wab0, be0, Afl, Bbf);
    edge_pass<<<2500, 256, 0, stream>>>(Bbf, Afl, es, Wef0, cstart, hist, hbf, parent + 128);

    // ---- layer 2 ----
    gemmAB<<<313, 256, 0, stream>>>(hbf, Wab1, be1, Afl, Bbf);
    edge_pass<<<2500, 256, 0, stream>>>(Bbf, Afl, es, Wef1, cstart, hist, hbf, parent + 256);

    final_gemm<<<1, 1024, 0, stream>>>((const float*)parent, Wp, bp, (float*)d_out);
}